// Round 1
// baseline (941.778 us; speedup 1.0000x reference)
//
#include <hip/hip_runtime.h>
#include <cstdint>
#include <cstddef>

#define NNODES   4096        // B
#define DIM      256         // D
#define NPAIRS   8128        // 128*127/2
#define NEDGE_IN 131072      // E
#define M_EDGES  (NEDGE_IN + NNODES)
#define NEG_SLOPE 0.2f
#define EPS_G     1e-10f

// ---------------- block reductions (256 threads = 4 waves) ----------------
__device__ __forceinline__ float blockReduceMax(float v, float* red) {
  #pragma unroll
  for (int o = 32; o > 0; o >>= 1) v = fmaxf(v, __shfl_down(v, o, 64));
  int lane = threadIdx.x & 63, wid = threadIdx.x >> 6;
  if (lane == 0) red[wid] = v;
  __syncthreads();
  if (threadIdx.x == 0) {
    float r = red[0];
    #pragma unroll
    for (int i = 1; i < 4; ++i) r = fmaxf(r, red[i]);
    red[0] = r;
  }
  __syncthreads();
  float r = red[0];
  __syncthreads();
  return r;
}

__device__ __forceinline__ float blockReduceSum(float v, float* red) {
  #pragma unroll
  for (int o = 32; o > 0; o >>= 1) v += __shfl_down(v, o, 64);
  int lane = threadIdx.x & 63, wid = threadIdx.x >> 6;
  if (lane == 0) red[wid] = v;
  __syncthreads();
  if (threadIdx.x == 0) {
    float r = red[0];
    #pragma unroll
    for (int i = 1; i < 4; ++i) r += red[i];
    red[0] = r;
  }
  __syncthreads();
  float r = red[0];
  __syncthreads();
  return r;
}

// ---------------- CSR build ----------------
__global__ void k_deg(const int* __restrict__ ei, int* __restrict__ deg) {
  int e = blockIdx.x * 256 + threadIdx.x;
  if (e >= M_EDGES) return;
  int dst = (e < NEDGE_IN) ? ei[NEDGE_IN + e] : (e - NEDGE_IN);
  atomicAdd(&deg[dst], 1);
}

__global__ void k_scan(const int* __restrict__ deg, int* __restrict__ offs,
                       int* __restrict__ cursor) {
  __shared__ int lds[1024];
  int t = threadIdx.x;
  int4 d = *(const int4*)&deg[t * 4];
  int s = d.x + d.y + d.z + d.w;
  lds[t] = s;
  __syncthreads();
  for (int off = 1; off < 1024; off <<= 1) {
    int v = 0;
    if (t >= off) v = lds[t - off];
    __syncthreads();
    if (t >= off) lds[t] += v;
    __syncthreads();
  }
  int base = lds[t] - s;               // exclusive prefix
  int o0 = base, o1 = o0 + d.x, o2 = o1 + d.y, o3 = o2 + d.z;
  offs[t*4+0] = o0; offs[t*4+1] = o1; offs[t*4+2] = o2; offs[t*4+3] = o3;
  cursor[t*4+0] = o0; cursor[t*4+1] = o1; cursor[t*4+2] = o2; cursor[t*4+3] = o3;
  if (t == 1023) offs[4096] = lds[1023];
}

__global__ void k_scatter(const int* __restrict__ ei, int* __restrict__ cursor,
                          int* __restrict__ srcs) {
  int e = blockIdx.x * 256 + threadIdx.x;
  if (e >= M_EDGES) return;
  int src, dst;
  if (e < NEDGE_IN) { src = ei[e]; dst = ei[NEDGE_IN + e]; }
  else              { src = dst = e - NEDGE_IN; }
  int pos = atomicAdd(&cursor[dst], 1);
  srcs[pos] = src;
}

// ---------------- Wdiff / cdiff precompute ----------------
__global__ void k_wdiff(const float* __restrict__ fcW, const float* __restrict__ fcb,
                        float* __restrict__ Wd, float* __restrict__ cdf) {
  int p = blockIdx.x * 256 + threadIdx.x;
  int k = blockIdx.y;
  if (p >= NPAIRS) return;
  Wd[(size_t)k * NPAIRS + p] =
      fcW[(size_t)k * (2 * NPAIRS) + 2 * p] - fcW[(size_t)k * (2 * NPAIRS) + 2 * p + 1];
  if (k == 0) cdf[p] = fcb[2 * p] - fcb[2 * p + 1];
}

// ---------------- fp32 tiled GEMM: C(Mx256) = A(Mx256) * B(256x256) ----------------
__global__ __launch_bounds__(256) void k_gemm_h(const float* __restrict__ A,
                                                const float* __restrict__ Bm,
                                                float* __restrict__ C) {
  __shared__ float As[16][64];
  __shared__ float Bs[16][64];
  int tid = threadIdx.x;
  int rowBase = blockIdx.x * 64, colBase = blockIdx.y * 64;
  int tx = tid & 15, ty = tid >> 4;
  int ar = tid >> 2, ac = (tid & 3) << 2;
  int bkr = tid >> 6, bcc = tid & 63;
  float acc[4][4] = {{0.f}};
  for (int k0 = 0; k0 < DIM; k0 += 16) {
    float4 av = *(const float4*)&A[(size_t)(rowBase + ar) * DIM + k0 + ac];
    As[ac+0][ar] = av.x; As[ac+1][ar] = av.y; As[ac+2][ar] = av.z; As[ac+3][ar] = av.w;
    #pragma unroll
    for (int j = 0; j < 4; ++j)
      Bs[bkr + 4*j][bcc] = Bm[(size_t)(k0 + bkr + 4*j) * 256 + colBase + bcc];
    __syncthreads();
    #pragma unroll
    for (int kk = 0; kk < 16; ++kk) {
      float4 a4 = *(const float4*)&As[kk][ty << 2];
      float4 b4 = *(const float4*)&Bs[kk][tx << 2];
      float a[4] = {a4.x, a4.y, a4.z, a4.w};
      float b[4] = {b4.x, b4.y, b4.z, b4.w};
      #pragma unroll
      for (int i = 0; i < 4; ++i)
        #pragma unroll
        for (int j = 0; j < 4; ++j) acc[i][j] = fmaf(a[i], b[j], acc[i][j]);
    }
    __syncthreads();
  }
  #pragma unroll
  for (int i = 0; i < 4; ++i) {
    int r = rowBase + (ty << 2) + i;
    #pragma unroll
    for (int j = 0; j < 4; ++j)
      C[(size_t)r * 256 + colBase + (tx << 2) + j] = acc[i][j];
  }
}

// ---------------- pair GEMM + gumbel-compare epilogue → adj bytes ----------------
__global__ __launch_bounds__(256) void k_gemm_pairs(const float* __restrict__ A,
                                                    const float* __restrict__ Bm,
                                                    const float* __restrict__ cdf,
                                                    const float* __restrict__ gumbel,
                                                    uint8_t* __restrict__ adjb) {
  __shared__ float As[16][64];
  __shared__ float Bs[16][64];
  int tid = threadIdx.x;
  int rowBase = blockIdx.x * 64, colBase = blockIdx.y * 64;
  int tx = tid & 15, ty = tid >> 4;
  int ar = tid >> 2, ac = (tid & 3) << 2;
  int bkr = tid >> 6, bcc = tid & 63;
  float acc[4][4] = {{0.f}};
  for (int k0 = 0; k0 < DIM; k0 += 16) {
    float4 av = *(const float4*)&A[(size_t)(rowBase + ar) * DIM + k0 + ac];
    As[ac+0][ar] = av.x; As[ac+1][ar] = av.y; As[ac+2][ar] = av.z; As[ac+3][ar] = av.w;
    #pragma unroll
    for (int j = 0; j < 4; ++j)
      Bs[bkr + 4*j][bcc] = Bm[(size_t)(k0 + bkr + 4*j) * NPAIRS + colBase + bcc];
    __syncthreads();
    #pragma unroll
    for (int kk = 0; kk < 16; ++kk) {
      float4 a4 = *(const float4*)&As[kk][ty << 2];
      float4 b4 = *(const float4*)&Bs[kk][tx << 2];
      float a[4] = {a4.x, a4.y, a4.z, a4.w};
      float b[4] = {b4.x, b4.y, b4.z, b4.w};
      #pragma unroll
      for (int i = 0; i < 4; ++i)
        #pragma unroll
        for (int j = 0; j < 4; ++j) acc[i][j] = fmaf(a[i], b[j], acc[i][j]);
    }
    __syncthreads();
  }
  #pragma unroll
  for (int i = 0; i < 4; ++i) {
    int r = rowBase + (ty << 2) + i;
    #pragma unroll
    for (int j = 0; j < 4; ++j) {
      int c = colBase + (tx << 2) + j;
      float dlt = acc[i][j] + cdf[c];
      float2 u = *(const float2*)&gumbel[((size_t)r * NPAIRS + c) * 2];
      float g0 = -logf(-logf(u.x + EPS_G) + EPS_G);
      float g1 = -logf(-logf(u.y + EPS_G) + EPS_G);
      adjb[(size_t)r * NPAIRS + c] = (dlt >= (g1 - g0)) ? (uint8_t)1 : (uint8_t)0;
    }
  }
}

// ---------------- per-row attention dots ----------------
__global__ __launch_bounds__(256) void k_rowdot(const float* __restrict__ h,
                                                const float* __restrict__ asrc,
                                                const float* __restrict__ adst,
                                                float* __restrict__ a_s,
                                                float* __restrict__ a_d) {
  __shared__ float red[4];
  int n = blockIdx.x, t = threadIdx.x;
  float hv = h[(size_t)n * DIM + t];
  float vs = blockReduceSum(hv * asrc[t], red);
  float vd = blockReduceSum(hv * adst[t], red);
  if (t == 0) { a_s[n] = vs; a_d[n] = vd; }
}

// ---------------- segment softmax + aggregation (one block per dst node) ----------------
__global__ __launch_bounds__(256) void k_agg(const float* __restrict__ h,
                                             const float* __restrict__ a_s,
                                             const float* __restrict__ a_d,
                                             const int* __restrict__ offs,
                                             const int* __restrict__ srcs,
                                             const float* __restrict__ bias,
                                             float* __restrict__ xout) {
  __shared__ float red[4];
  int n = blockIdx.x, t = threadIdx.x;
  int beg = offs[n], end = offs[n + 1];
  float ad = a_d[n];

  float m = -3.0e38f;
  for (int i = beg + t; i < end; i += 256) {
    float e = a_s[srcs[i]] + ad;
    e = (e >= 0.f) ? e : NEG_SLOPE * e;
    m = fmaxf(m, e);
  }
  m = blockReduceMax(m, red);

  float s = 0.f;
  for (int i = beg + t; i < end; i += 256) {
    float e = a_s[srcs[i]] + ad;
    e = (e >= 0.f) ? e : NEG_SLOPE * e;
    s += expf(e - m);
  }
  s = blockReduceSum(s, red);

  float acc = 0.f;
  for (int i = beg; i < end; ++i) {
    int src = srcs[i];
    float e = a_s[src] + ad;
    e = (e >= 0.f) ? e : NEG_SLOPE * e;
    float alpha = expf(e - m) / s;
    acc = fmaf(alpha, h[(size_t)src * DIM + t], acc);
  }
  xout[(size_t)n * DIM + t] = acc + bias[t];
}

// ---------------- expand adj bytes → symmetric 128x128 output ----------------
__global__ __launch_bounds__(256) void k_expand(const uint8_t* __restrict__ adjb,
                                                float* __restrict__ out) {
  int n = blockIdx.x;
  const uint8_t* ab = adjb + (size_t)n * NPAIRS;
  float* o = out + (size_t)n * 16384;
  for (int idx = threadIdx.x; idx < 16384; idx += 256) {
    int i = idx >> 7, j = idx & 127;
    float v = 0.f;
    if (i < j)      v = (float)ab[i * (255 - i) / 2 + (j - i - 1)];
    else if (i > j) v = (float)ab[j * (255 - j) / 2 + (i - j - 1)];
    o[idx] = v;
  }
}

extern "C" void kernel_launch(void* const* d_in, const int* in_sizes, int n_in,
                              void* d_out, int out_size, void* d_ws, size_t ws_size,
                              hipStream_t stream) {
  const float* x      = (const float*)d_in[0];
  const int*   ei     = (const int*)d_in[1];
  const float* gumbel = (const float*)d_in[2];
  const float* gatW   = (const float*)d_in[3];
  const float* a_src  = (const float*)d_in[4];
  const float* a_dst  = (const float*)d_in[5];
  const float* gatB   = (const float*)d_in[6];
  const float* fcW    = (const float*)d_in[7];
  const float* fcb    = (const float*)d_in[8];
  float* out = (float*)d_out;

  char* ws = (char*)d_ws;
  size_t off = 0;
  auto alloc = [&](size_t bytes) -> void* {
    void* p = ws + off;
    off += (bytes + 255) & ~(size_t)255;
    return p;
  };
  float* xb0   = (float*)alloc((size_t)NNODES * DIM * 4);
  float* xb1   = (float*)alloc((size_t)NNODES * DIM * 4);
  float* h     = (float*)alloc((size_t)NNODES * DIM * 4);
  float* as_   = (float*)alloc(NNODES * 4);
  float* ad_   = (float*)alloc(NNODES * 4);
  int*   deg   = (int*)alloc(NNODES * 4);
  int*   offs  = (int*)alloc((NNODES + 1) * 4);
  int*   cursor= (int*)alloc(NNODES * 4);
  int*   srcs  = (int*)alloc((size_t)M_EDGES * 4);
  float* Wd    = (float*)alloc((size_t)DIM * NPAIRS * 4);
  float* cdf   = (float*)alloc(NPAIRS * 4);
  uint8_t* adjb= (uint8_t*)alloc((size_t)NNODES * NPAIRS);

  dim3 b256(256);

  hipMemsetAsync(deg, 0, NNODES * 4, stream);
  k_wdiff<<<dim3(32, DIM), b256, 0, stream>>>(fcW, fcb, Wd, cdf);
  k_deg<<<dim3((M_EDGES + 255) / 256), b256, 0, stream>>>(ei, deg);
  k_scan<<<dim3(1), dim3(1024), 0, stream>>>(deg, offs, cursor);
  k_scatter<<<dim3((M_EDGES + 255) / 256), b256, 0, stream>>>(ei, cursor, srcs);

  const float* xin = x;
  float* bufs[2] = {xb0, xb1};
  for (int l = 0; l < 3; ++l) {
    float* xout = bufs[l & 1];
    k_gemm_h<<<dim3(64, 4), b256, 0, stream>>>(xin, gatW + (size_t)l * DIM * DIM, h);
    k_rowdot<<<dim3(NNODES), b256, 0, stream>>>(h, a_src + (size_t)l * DIM,
                                                a_dst + (size_t)l * DIM, as_, ad_);
    k_agg<<<dim3(NNODES), b256, 0, stream>>>(h, as_, ad_, offs, srcs,
                                             gatB + (size_t)l * DIM, xout);
    xin = xout;
  }

  k_gemm_pairs<<<dim3(64, 127), b256, 0, stream>>>(xin, Wd, cdf, gumbel, adjb);
  k_expand<<<dim3(NNODES), b256, 0, stream>>>(adjb, out);
}

// Round 2
// 901.391 us; speedup vs baseline: 1.0448x; 1.0448x over previous
//
#include <hip/hip_runtime.h>
#include <cstdint>
#include <cstddef>

#define NNODES   4096        // B
#define DIM      256         // D
#define NPAIRS   8128        // 128*127/2
#define NEDGE_IN 131072      // E
#define M_EDGES  (NEDGE_IN + NNODES)
#define NEG_SLOPE 0.2f
#define EPS_G     1e-10f

// ---------------- block reductions (256 threads = 4 waves) ----------------
__device__ __forceinline__ float blockReduceMax(float v, float* red) {
  #pragma unroll
  for (int o = 32; o > 0; o >>= 1) v = fmaxf(v, __shfl_down(v, o, 64));
  int lane = threadIdx.x & 63, wid = threadIdx.x >> 6;
  if (lane == 0) red[wid] = v;
  __syncthreads();
  if (threadIdx.x == 0) {
    float r = red[0];
    #pragma unroll
    for (int i = 1; i < 4; ++i) r = fmaxf(r, red[i]);
    red[0] = r;
  }
  __syncthreads();
  float r = red[0];
  __syncthreads();
  return r;
}

__device__ __forceinline__ float blockReduceSum(float v, float* red) {
  #pragma unroll
  for (int o = 32; o > 0; o >>= 1) v += __shfl_down(v, o, 64);
  int lane = threadIdx.x & 63, wid = threadIdx.x >> 6;
  if (lane == 0) red[wid] = v;
  __syncthreads();
  if (threadIdx.x == 0) {
    float r = red[0];
    #pragma unroll
    for (int i = 1; i < 4; ++i) r += red[i];
    red[0] = r;
  }
  __syncthreads();
  float r = red[0];
  __syncthreads();
  return r;
}

// ---------------- CSR build ----------------
__global__ void k_deg(const int* __restrict__ ei, int* __restrict__ deg) {
  int e = blockIdx.x * 256 + threadIdx.x;
  if (e >= M_EDGES) return;
  int dst = (e < NEDGE_IN) ? ei[NEDGE_IN + e] : (e - NEDGE_IN);
  atomicAdd(&deg[dst], 1);
}

__global__ void k_scan(const int* __restrict__ deg, int* __restrict__ offs,
                       int* __restrict__ cursor) {
  __shared__ int lds[1024];
  int t = threadIdx.x;
  int4 d = *(const int4*)&deg[t * 4];
  int s = d.x + d.y + d.z + d.w;
  lds[t] = s;
  __syncthreads();
  for (int off = 1; off < 1024; off <<= 1) {
    int v = 0;
    if (t >= off) v = lds[t - off];
    __syncthreads();
    if (t >= off) lds[t] += v;
    __syncthreads();
  }
  int base = lds[t] - s;               // exclusive prefix
  int o0 = base, o1 = o0 + d.x, o2 = o1 + d.y, o3 = o2 + d.z;
  offs[t*4+0] = o0; offs[t*4+1] = o1; offs[t*4+2] = o2; offs[t*4+3] = o3;
  cursor[t*4+0] = o0; cursor[t*4+1] = o1; cursor[t*4+2] = o2; cursor[t*4+3] = o3;
  if (t == 1023) offs[4096] = lds[1023];
}

__global__ void k_scatter(const int* __restrict__ ei, int* __restrict__ cursor,
                          int* __restrict__ srcs) {
  int e = blockIdx.x * 256 + threadIdx.x;
  if (e >= M_EDGES) return;
  int src, dst;
  if (e < NEDGE_IN) { src = ei[e]; dst = ei[NEDGE_IN + e]; }
  else              { src = dst = e - NEDGE_IN; }
  int pos = atomicAdd(&cursor[dst], 1);
  srcs[pos] = src;
}

// ---------------- Wdiff / cdiff precompute ----------------
__global__ void k_wdiff(const float* __restrict__ fcW, const float* __restrict__ fcb,
                        float* __restrict__ Wd, float* __restrict__ cdf) {
  int p = blockIdx.x * 256 + threadIdx.x;
  int k = blockIdx.y;
  if (p >= NPAIRS) return;
  Wd[(size_t)k * NPAIRS + p] =
      fcW[(size_t)k * (2 * NPAIRS) + 2 * p] - fcW[(size_t)k * (2 * NPAIRS) + 2 * p + 1];
  if (k == 0) cdf[p] = fcb[2 * p] - fcb[2 * p + 1];
}

// ---------------- fp32 tiled GEMM: C(Mx256) = A(Mx256) * B(256x256) ----------------
__global__ __launch_bounds__(256) void k_gemm_h(const float* __restrict__ A,
                                                const float* __restrict__ Bm,
                                                float* __restrict__ C) {
  __shared__ float As[16][64];
  __shared__ float Bs[16][64];
  int tid = threadIdx.x;
  int rowBase = blockIdx.x * 64, colBase = blockIdx.y * 64;
  int tx = tid & 15, ty = tid >> 4;
  int ar = tid >> 2, ac = (tid & 3) << 2;
  int bkr = tid >> 6, bcc = tid & 63;
  float acc[4][4] = {{0.f}};
  for (int k0 = 0; k0 < DIM; k0 += 16) {
    float4 av = *(const float4*)&A[(size_t)(rowBase + ar) * DIM + k0 + ac];
    As[ac+0][ar] = av.x; As[ac+1][ar] = av.y; As[ac+2][ar] = av.z; As[ac+3][ar] = av.w;
    #pragma unroll
    for (int j = 0; j < 4; ++j)
      Bs[bkr + 4*j][bcc] = Bm[(size_t)(k0 + bkr + 4*j) * 256 + colBase + bcc];
    __syncthreads();
    #pragma unroll
    for (int kk = 0; kk < 16; ++kk) {
      float4 a4 = *(const float4*)&As[kk][ty << 2];
      float4 b4 = *(const float4*)&Bs[kk][tx << 2];
      float a[4] = {a4.x, a4.y, a4.z, a4.w};
      float b[4] = {b4.x, b4.y, b4.z, b4.w};
      #pragma unroll
      for (int i = 0; i < 4; ++i)
        #pragma unroll
        for (int j = 0; j < 4; ++j) acc[i][j] = fmaf(a[i], b[j], acc[i][j]);
    }
    __syncthreads();
  }
  #pragma unroll
  for (int i = 0; i < 4; ++i) {
    int r = rowBase + (ty << 2) + i;
    #pragma unroll
    for (int j = 0; j < 4; ++j)
      C[(size_t)r * 256 + colBase + (tx << 2) + j] = acc[i][j];
  }
}

// ---------------- pair GEMM (128x128 tile, 8x8/thread) + gumbel epilogue ----------------
__global__ __launch_bounds__(256) void k_gemm_pairs(const float* __restrict__ A,
                                                    const float* __restrict__ Bm,
                                                    const float* __restrict__ cdf,
                                                    const float* __restrict__ gumbel,
                                                    uint8_t* __restrict__ adjb) {
  __shared__ float As[16][128];
  __shared__ float Bs[16][128];
  int tid = threadIdx.x;
  int tx = tid & 15, ty = tid >> 4;
  int rowBase = blockIdx.x * 128, colBase = blockIdx.y * 128;

  int arow = tid >> 1;            // 0..127
  int akh  = (tid & 1) * 8;       // 0 or 8
  int bkr  = tid >> 4;            // 0..15
  int bcc  = (tid & 15) * 8;      // 0..120

  // acc[q][i*4+j], q = ih*2+jh (row-half, col-half quadrants)
  float acc[4][16];
  #pragma unroll
  for (int q = 0; q < 4; ++q)
    #pragma unroll
    for (int r = 0; r < 16; ++r) acc[q][r] = 0.f;

  const float* Arow = A + (size_t)(rowBase + arow) * DIM + akh;
  bool bv0 = (colBase + bcc)     < NPAIRS;   // float4 at bcc   (NPAIRS%4==0 so all-or-none)
  bool bv1 = (colBase + bcc + 4) < NPAIRS;

  for (int k0 = 0; k0 < DIM; k0 += 16) {
    float4 ga0 = *(const float4*)(Arow + k0);
    float4 ga1 = *(const float4*)(Arow + k0 + 4);
    const float* Bp = Bm + (size_t)(k0 + bkr) * NPAIRS + colBase + bcc;
    float4 gb0 = bv0 ? *(const float4*)Bp       : make_float4(0.f,0.f,0.f,0.f);
    float4 gb1 = bv1 ? *(const float4*)(Bp + 4) : make_float4(0.f,0.f,0.f,0.f);
    __syncthreads();
    As[akh+0][arow] = ga0.x; As[akh+1][arow] = ga0.y;
    As[akh+2][arow] = ga0.z; As[akh+3][arow] = ga0.w;
    As[akh+4][arow] = ga1.x; As[akh+5][arow] = ga1.y;
    As[akh+6][arow] = ga1.z; As[akh+7][arow] = ga1.w;
    *(float4*)&Bs[bkr][bcc]     = gb0;
    *(float4*)&Bs[bkr][bcc + 4] = gb1;
    __syncthreads();
    #pragma unroll
    for (int kk = 0; kk < 16; ++kk) {
      float4 a0 = *(const float4*)&As[kk][ty * 4];
      float4 a1 = *(const float4*)&As[kk][64 + ty * 4];
      float4 b0 = *(const float4*)&Bs[kk][tx * 4];
      float4 b1 = *(const float4*)&Bs[kk][64 + tx * 4];
      float av[8] = {a0.x,a0.y,a0.z,a0.w, a1.x,a1.y,a1.z,a1.w};
      float bv[8] = {b0.x,b0.y,b0.z,b0.w, b1.x,b1.y,b1.z,b1.w};
      #pragma unroll
      for (int ih = 0; ih < 2; ++ih)
        #pragma unroll
        for (int jh = 0; jh < 2; ++jh)
          #pragma unroll
          for (int i = 0; i < 4; ++i)
            #pragma unroll
            for (int j = 0; j < 4; ++j)
              acc[ih*2+jh][i*4+j] = fmaf(av[ih*4+i], bv[jh*4+j], acc[ih*2+jh][i*4+j]);
    }
  }

  // epilogue: dlt = acc + cdiff; keep = dlt >= g1-g0
  #pragma unroll
  for (int ih = 0; ih < 2; ++ih) {
    #pragma unroll
    for (int i = 0; i < 4; ++i) {
      int r = rowBase + ih * 64 + ty * 4 + i;
      #pragma unroll
      for (int jh = 0; jh < 2; ++jh) {
        int cb = colBase + jh * 64 + tx * 4;
        if (cb < NPAIRS) {
          const float4* gp = (const float4*)&gumbel[((size_t)r * NPAIRS + cb) * 2];
          float4 g01 = gp[0];   // cols cb, cb+1 (u0,u1 each)
          float4 g23 = gp[1];   // cols cb+2, cb+3
          float u0[4] = {g01.x, g01.z, g23.x, g23.z};
          float u1[4] = {g01.y, g01.w, g23.y, g23.w};
          uint8_t res[4];
          #pragma unroll
          for (int j = 0; j < 4; ++j) {
            float dlt = acc[ih*2+jh][i*4+j] + cdf[cb + j];
            float g0 = -logf(-logf(u0[j] + EPS_G) + EPS_G);
            float g1 = -logf(-logf(u1[j] + EPS_G) + EPS_G);
            res[j] = (dlt >= (g1 - g0)) ? (uint8_t)1 : (uint8_t)0;
          }
          *(uchar4*)&adjb[(size_t)r * NPAIRS + cb] =
              make_uchar4(res[0], res[1], res[2], res[3]);
        }
      }
    }
  }
}

// ---------------- per-row attention dots ----------------
__global__ __launch_bounds__(256) void k_rowdot(const float* __restrict__ h,
                                                const float* __restrict__ asrc,
                                                const float* __restrict__ adst,
                                                float* __restrict__ a_s,
                                                float* __restrict__ a_d) {
  __shared__ float red[4];
  int n = blockIdx.x, t = threadIdx.x;
  float hv = h[(size_t)n * DIM + t];
  float vs = blockReduceSum(hv * asrc[t], red);
  float vd = blockReduceSum(hv * adst[t], red);
  if (t == 0) { a_s[n] = vs; a_d[n] = vd; }
}

// ---------------- segment softmax + aggregation (one block per dst node) ----------------
__global__ __launch_bounds__(256) void k_agg(const float* __restrict__ h,
                                             const float* __restrict__ a_s,
                                             const float* __restrict__ a_d,
                                             const int* __restrict__ offs,
                                             const int* __restrict__ srcs,
                                             const float* __restrict__ bias,
                                             float* __restrict__ xout) {
  __shared__ float red[4];
  int n = blockIdx.x, t = threadIdx.x;
  int beg = offs[n], end = offs[n + 1];
  float ad = a_d[n];

  float m = -3.0e38f;
  for (int i = beg + t; i < end; i += 256) {
    float e = a_s[srcs[i]] + ad;
    e = (e >= 0.f) ? e : NEG_SLOPE * e;
    m = fmaxf(m, e);
  }
  m = blockReduceMax(m, red);

  float s = 0.f;
  for (int i = beg + t; i < end; i += 256) {
    float e = a_s[srcs[i]] + ad;
    e = (e >= 0.f) ? e : NEG_SLOPE * e;
    s += expf(e - m);
  }
  s = blockReduceSum(s, red);

  float acc = 0.f;
  for (int i = beg; i < end; ++i) {
    int src = srcs[i];
    float e = a_s[src] + ad;
    e = (e >= 0.f) ? e : NEG_SLOPE * e;
    float alpha = expf(e - m) / s;
    acc = fmaf(alpha, h[(size_t)src * DIM + t], acc);
  }
  xout[(size_t)n * DIM + t] = acc + bias[t];
}

// ---------------- expand adj bytes → symmetric 128x128 output ----------------
__global__ __launch_bounds__(256) void k_expand(const uint8_t* __restrict__ adjb,
                                                float* __restrict__ out) {
  int n = blockIdx.x;
  const uint8_t* ab = adjb + (size_t)n * NPAIRS;
  float4* o = (float4*)(out + (size_t)n * 16384);
  for (int q = threadIdx.x; q < 4096; q += 256) {
    int i = q >> 5;            // row (= (q*4)>>7)
    int j0 = (q & 31) * 4;
    float v[4];
    #pragma unroll
    for (int j = 0; j < 4; ++j) {
      int jj = j0 + j;
      float x = 0.f;
      if (i < jj)      x = (float)ab[i * (255 - i) / 2 + (jj - i - 1)];
      else if (i > jj) x = (float)ab[jj * (255 - jj) / 2 + (i - jj - 1)];
      v[j] = x;
    }
    o[q] = make_float4(v[0], v[1], v[2], v[3]);
  }
}

extern "C" void kernel_launch(void* const* d_in, const int* in_sizes, int n_in,
                              void* d_out, int out_size, void* d_ws, size_t ws_size,
                              hipStream_t stream) {
  const float* x      = (const float*)d_in[0];
  const int*   ei     = (const int*)d_in[1];
  const float* gumbel = (const float*)d_in[2];
  const float* gatW   = (const float*)d_in[3];
  const float* a_src  = (const float*)d_in[4];
  const float* a_dst  = (const float*)d_in[5];
  const float* gatB   = (const float*)d_in[6];
  const float* fcW    = (const float*)d_in[7];
  const float* fcb    = (const float*)d_in[8];
  float* out = (float*)d_out;

  char* ws = (char*)d_ws;
  size_t off = 0;
  auto alloc = [&](size_t bytes) -> void* {
    void* p = ws + off;
    off += (bytes + 255) & ~(size_t)255;
    return p;
  };
  float* xb0   = (float*)alloc((size_t)NNODES * DIM * 4);
  float* xb1   = (float*)alloc((size_t)NNODES * DIM * 4);
  float* h     = (float*)alloc((size_t)NNODES * DIM * 4);
  float* as_   = (float*)alloc(NNODES * 4);
  float* ad_   = (float*)alloc(NNODES * 4);
  int*   deg   = (int*)alloc(NNODES * 4);
  int*   offs  = (int*)alloc((NNODES + 1) * 4);
  int*   cursor= (int*)alloc(NNODES * 4);
  int*   srcs  = (int*)alloc((size_t)M_EDGES * 4);
  float* Wd    = (float*)alloc((size_t)DIM * NPAIRS * 4);
  float* cdf   = (float*)alloc(NPAIRS * 4);
  uint8_t* adjb= (uint8_t*)alloc((size_t)NNODES * NPAIRS);

  dim3 b256(256);

  hipMemsetAsync(deg, 0, NNODES * 4, stream);
  k_wdiff<<<dim3(32, DIM), b256, 0, stream>>>(fcW, fcb, Wd, cdf);
  k_deg<<<dim3((M_EDGES + 255) / 256), b256, 0, stream>>>(ei, deg);
  k_scan<<<dim3(1), dim3(1024), 0, stream>>>(deg, offs, cursor);
  k_scatter<<<dim3((M_EDGES + 255) / 256), b256, 0, stream>>>(ei, cursor, srcs);

  const float* xin = x;
  float* bufs[2] = {xb0, xb1};
  for (int l = 0; l < 3; ++l) {
    float* xout = bufs[l & 1];
    k_gemm_h<<<dim3(64, 4), b256, 0, stream>>>(xin, gatW + (size_t)l * DIM * DIM, h);
    k_rowdot<<<dim3(NNODES), b256, 0, stream>>>(h, a_src + (size_t)l * DIM,
                                                a_dst + (size_t)l * DIM, as_, ad_);
    k_agg<<<dim3(NNODES), b256, 0, stream>>>(h, as_, ad_, offs, srcs,
                                             gatB + (size_t)l * DIM, xout);
    xin = xout;
  }

  k_gemm_pairs<<<dim3(32, 64), b256, 0, stream>>>(xin, Wd, cdf, gumbel, adjb);
  k_expand<<<dim3(NNODES), b256, 0, stream>>>(adjb, out);
}

// Round 3
// 889.045 us; speedup vs baseline: 1.0593x; 1.0139x over previous
//
#include <hip/hip_runtime.h>
#include <cstdint>
#include <cstddef>

#define NNODES   4096        // B
#define DIM      256         // D
#define NPAIRS   8128        // 128*127/2
#define NEDGE_IN 131072      // E
#define M_EDGES  (NEDGE_IN + NNODES)
#define NEG_SLOPE 0.2f
#define EPS_G     1e-10f

// ---------------- block reductions (256 threads = 4 waves) ----------------
__device__ __forceinline__ float blockReduceSum(float v, float* red) {
  #pragma unroll
  for (int o = 32; o > 0; o >>= 1) v += __shfl_down(v, o, 64);
  int lane = threadIdx.x & 63, wid = threadIdx.x >> 6;
  if (lane == 0) red[wid] = v;
  __syncthreads();
  if (threadIdx.x == 0) {
    float r = red[0];
    #pragma unroll
    for (int i = 1; i < 4; ++i) r += red[i];
    red[0] = r;
  }
  __syncthreads();
  float r = red[0];
  __syncthreads();
  return r;
}

// ---------------- CSR build ----------------
__global__ void k_deg(const int* __restrict__ ei, int* __restrict__ deg) {
  int e = blockIdx.x * 256 + threadIdx.x;
  if (e >= M_EDGES) return;
  int dst = (e < NEDGE_IN) ? ei[NEDGE_IN + e] : (e - NEDGE_IN);
  atomicAdd(&deg[dst], 1);
}

__global__ void k_scan(const int* __restrict__ deg, int* __restrict__ offs,
                       int* __restrict__ cursor) {
  __shared__ int lds[1024];
  int t = threadIdx.x;
  int4 d = *(const int4*)&deg[t * 4];
  int s = d.x + d.y + d.z + d.w;
  lds[t] = s;
  __syncthreads();
  for (int off = 1; off < 1024; off <<= 1) {
    int v = 0;
    if (t >= off) v = lds[t - off];
    __syncthreads();
    if (t >= off) lds[t] += v;
    __syncthreads();
  }
  int base = lds[t] - s;               // exclusive prefix
  int o0 = base, o1 = o0 + d.x, o2 = o1 + d.y, o3 = o2 + d.z;
  offs[t*4+0] = o0; offs[t*4+1] = o1; offs[t*4+2] = o2; offs[t*4+3] = o3;
  cursor[t*4+0] = o0; cursor[t*4+1] = o1; cursor[t*4+2] = o2; cursor[t*4+3] = o3;
  if (t == 1023) offs[4096] = lds[1023];
}

__global__ void k_scatter(const int* __restrict__ ei, int* __restrict__ cursor,
                          int* __restrict__ srcs) {
  int e = blockIdx.x * 256 + threadIdx.x;
  if (e >= M_EDGES) return;
  int src, dst;
  if (e < NEDGE_IN) { src = ei[e]; dst = ei[NEDGE_IN + e]; }
  else              { src = dst = e - NEDGE_IN; }
  int pos = atomicAdd(&cursor[dst], 1);
  srcs[pos] = src;
}

// ---------------- Wdiff / cdiff precompute ----------------
__global__ void k_wdiff(const float* __restrict__ fcW, const float* __restrict__ fcb,
                        float* __restrict__ Wd, float* __restrict__ cdf) {
  int p = blockIdx.x * 256 + threadIdx.x;
  int k = blockIdx.y;
  if (p >= NPAIRS) return;
  Wd[(size_t)k * NPAIRS + p] =
      fcW[(size_t)k * (2 * NPAIRS) + 2 * p] - fcW[(size_t)k * (2 * NPAIRS) + 2 * p + 1];
  if (k == 0) cdf[p] = fcb[2 * p] - fcb[2 * p + 1];
}

// ---------------- transpose x (4096x256) -> At (256x4096) ----------------
__global__ __launch_bounds__(256) void k_transp(const float* __restrict__ A,
                                                float* __restrict__ At) {
  __shared__ float t[64][65];
  int bx = blockIdx.x * 64;   // row base (NNODES dim)
  int by = blockIdx.y * 64;   // col base (DIM dim)
  for (int i = threadIdx.x; i < 4096; i += 256) {
    int r = i >> 6, c = i & 63;
    t[r][c] = A[(size_t)(bx + r) * DIM + by + c];
  }
  __syncthreads();
  for (int i = threadIdx.x; i < 4096; i += 256) {
    int r = i >> 6, c = i & 63;
    At[(size_t)(by + r) * NNODES + bx + c] = t[c][r];
  }
}

// ---------------- fp32 tiled GEMM: C(Mx256) = A(Mx256) * B(256x256) ----------------
__global__ __launch_bounds__(256) void k_gemm_h(const float* __restrict__ A,
                                                const float* __restrict__ Bm,
                                                float* __restrict__ C) {
  __shared__ float As[16][64];
  __shared__ float Bs[16][64];
  int tid = threadIdx.x;
  int rowBase = blockIdx.x * 64, colBase = blockIdx.y * 64;
  int tx = tid & 15, ty = tid >> 4;
  int ar = tid >> 2, ac = (tid & 3) << 2;
  int bkr = tid >> 6, bcc = tid & 63;
  float acc[4][4] = {{0.f}};
  for (int k0 = 0; k0 < DIM; k0 += 16) {
    float4 av = *(const float4*)&A[(size_t)(rowBase + ar) * DIM + k0 + ac];
    As[ac+0][ar] = av.x; As[ac+1][ar] = av.y; As[ac+2][ar] = av.z; As[ac+3][ar] = av.w;
    #pragma unroll
    for (int j = 0; j < 4; ++j)
      Bs[bkr + 4*j][bcc] = Bm[(size_t)(k0 + bkr + 4*j) * 256 + colBase + bcc];
    __syncthreads();
    #pragma unroll
    for (int kk = 0; kk < 16; ++kk) {
      float4 a4 = *(const float4*)&As[kk][ty << 2];
      float4 b4 = *(const float4*)&Bs[kk][tx << 2];
      float a[4] = {a4.x, a4.y, a4.z, a4.w};
      float b[4] = {b4.x, b4.y, b4.z, b4.w};
      #pragma unroll
      for (int i = 0; i < 4; ++i)
        #pragma unroll
        for (int j = 0; j < 4; ++j) acc[i][j] = fmaf(a[i], b[j], acc[i][j]);
    }
    __syncthreads();
  }
  #pragma unroll
  for (int i = 0; i < 4; ++i) {
    int r = rowBase + (ty << 2) + i;
    #pragma unroll
    for (int j = 0; j < 4; ++j)
      C[(size_t)r * 256 + colBase + (tx << 2) + j] = acc[i][j];
  }
}

// ---------------- pair GEMM (256x128 tile, 16x8/thread) + gumbel epilogue ------------
// A is pre-transposed: At[k][row], k<256, row<4096.
__global__ __launch_bounds__(256, 2) void k_gemm_pairs(const float* __restrict__ At,
                                                       const float* __restrict__ Bm,
                                                       const float* __restrict__ cdf,
                                                       const float* __restrict__ gumbel,
                                                       uint8_t* __restrict__ adjb) {
  __shared__ float As[16][256];   // 16 KB
  __shared__ float Bs[16][128];   // 8 KB
  int tid = threadIdx.x;
  int tx = tid & 15;              // col group 0..15
  int ty = tid >> 4;              // row group 0..15
  int rowBase = blockIdx.x * 256, colBase = blockIdx.y * 128;

  int sk  = tid >> 4;             // staging k-row 0..15
  int arp = (tid & 15) * 16;      // A staging: 16 floats per thread
  int bcp = (tid & 15) * 8;       // B staging: 8 floats per thread

  bool bv0 = (colBase + bcp)     + 4 <= NPAIRS;
  bool bv1 = (colBase + bcp + 4) + 4 <= NPAIRS;

  // acc[q][h][i][j]: row = q*64 + ty*4 + i, col = h*64 + tx*4 + j
  float acc[4][2][4][4];
  #pragma unroll
  for (int q = 0; q < 4; ++q)
    #pragma unroll
    for (int h = 0; h < 2; ++h)
      #pragma unroll
      for (int i = 0; i < 4; ++i)
        #pragma unroll
        for (int j = 0; j < 4; ++j) acc[q][h][i][j] = 0.f;

  for (int k0 = 0; k0 < DIM; k0 += 16) {
    const float* Ap = At + (size_t)(k0 + sk) * NNODES + rowBase + arp;
    float4 ga0 = *(const float4*)(Ap + 0);
    float4 ga1 = *(const float4*)(Ap + 4);
    float4 ga2 = *(const float4*)(Ap + 8);
    float4 ga3 = *(const float4*)(Ap + 12);
    const float* Bp = Bm + (size_t)(k0 + sk) * NPAIRS + colBase + bcp;
    float4 gb0 = bv0 ? *(const float4*)(Bp + 0) : make_float4(0.f,0.f,0.f,0.f);
    float4 gb1 = bv1 ? *(const float4*)(Bp + 4) : make_float4(0.f,0.f,0.f,0.f);
    __syncthreads();
    *(float4*)&As[sk][arp + 0]  = ga0;
    *(float4*)&As[sk][arp + 4]  = ga1;
    *(float4*)&As[sk][arp + 8]  = ga2;
    *(float4*)&As[sk][arp + 12] = ga3;
    *(float4*)&Bs[sk][bcp + 0]  = gb0;
    *(float4*)&Bs[sk][bcp + 4]  = gb1;
    __syncthreads();
    #pragma unroll
    for (int kk = 0; kk < 16; ++kk) {
      float4 a0 = *(const float4*)&As[kk][  0 + ty * 4];
      float4 a1 = *(const float4*)&As[kk][ 64 + ty * 4];
      float4 a2 = *(const float4*)&As[kk][128 + ty * 4];
      float4 a3 = *(const float4*)&As[kk][192 + ty * 4];
      float4 b0 = *(const float4*)&Bs[kk][  0 + tx * 4];
      float4 b1 = *(const float4*)&Bs[kk][ 64 + tx * 4];
      float av[4][4] = {{a0.x,a0.y,a0.z,a0.w},{a1.x,a1.y,a1.z,a1.w},
                        {a2.x,a2.y,a2.z,a2.w},{a3.x,a3.y,a3.z,a3.w}};
      float bv[2][4] = {{b0.x,b0.y,b0.z,b0.w},{b1.x,b1.y,b1.z,b1.w}};
      #pragma unroll
      for (int q = 0; q < 4; ++q)
        #pragma unroll
        for (int h = 0; h < 2; ++h)
          #pragma unroll
          for (int i = 0; i < 4; ++i)
            #pragma unroll
            for (int j = 0; j < 4; ++j)
              acc[q][h][i][j] = fmaf(av[q][i], bv[h][j], acc[q][h][i][j]);
    }
  }

  // epilogue: dlt = acc + cdiff; keep = dlt >= g1-g0
  #pragma unroll
  for (int q = 0; q < 4; ++q) {
    #pragma unroll
    for (int i = 0; i < 4; ++i) {
      int r = rowBase + q * 64 + ty * 4 + i;
      #pragma unroll
      for (int h = 0; h < 2; ++h) {
        int cb = colBase + h * 64 + tx * 4;
        if (cb < NPAIRS) {
          const float4* gp = (const float4*)&gumbel[((size_t)r * NPAIRS + cb) * 2];
          float4 g01 = gp[0];
          float4 g23 = gp[1];
          float u0[4] = {g01.x, g01.z, g23.x, g23.z};
          float u1[4] = {g01.y, g01.w, g23.y, g23.w};
          uint8_t res[4];
          #pragma unroll
          for (int j = 0; j < 4; ++j) {
            float dlt = acc[q][h][i][j] + cdf[cb + j];
            float g0 = -logf(-logf(u0[j] + EPS_G) + EPS_G);
            float g1 = -logf(-logf(u1[j] + EPS_G) + EPS_G);
            res[j] = (dlt >= (g1 - g0)) ? (uint8_t)1 : (uint8_t)0;
          }
          *(uchar4*)&adjb[(size_t)r * NPAIRS + cb] =
              make_uchar4(res[0], res[1], res[2], res[3]);
        }
      }
    }
  }
}

// ---------------- per-row attention dots ----------------
__global__ __launch_bounds__(256) void k_rowdot(const float* __restrict__ h,
                                                const float* __restrict__ asrc,
                                                const float* __restrict__ adst,
                                                float* __restrict__ a_s,
                                                float* __restrict__ a_d) {
  __shared__ float red[4];
  int n = blockIdx.x, t = threadIdx.x;
  float hv = h[(size_t)n * DIM + t];
  float vs = blockReduceSum(hv * asrc[t], red);
  float vd = blockReduceSum(hv * adst[t], red);
  if (t == 0) { a_s[n] = vs; a_d[n] = vd; }
}

// ------- segment softmax + aggregation: one WAVE per dst node, float4 lanes -------
__global__ __launch_bounds__(256) void k_agg(const float* __restrict__ h,
                                             const float* __restrict__ a_s,
                                             const float* __restrict__ a_d,
                                             const int* __restrict__ offs,
                                             const int* __restrict__ srcs,
                                             const float* __restrict__ bias,
                                             float* __restrict__ xout) {
  int wid  = threadIdx.x >> 6;
  int lane = threadIdx.x & 63;
  int n = blockIdx.x * 4 + wid;
  int beg = offs[n], end = offs[n + 1];
  float ad = a_d[n];

  // phase 1: max
  float m = -3.0e38f;
  for (int i = beg + lane; i < end; i += 64) {
    float e = a_s[srcs[i]] + ad;
    e = (e >= 0.f) ? e : NEG_SLOPE * e;
    m = fmaxf(m, e);
  }
  #pragma unroll
  for (int o = 1; o < 64; o <<= 1) m = fmaxf(m, __shfl_xor(m, o, 64));

  // phase 2: sum
  float s = 0.f;
  for (int i = beg + lane; i < end; i += 64) {
    float e = a_s[srcs[i]] + ad;
    e = (e >= 0.f) ? e : NEG_SLOPE * e;
    s += expf(e - m);
  }
  #pragma unroll
  for (int o = 1; o < 64; o <<= 1) s += __shfl_xor(s, o, 64);

  // phase 3: weighted aggregation, float4 per lane (lane covers dims 4*lane..4*lane+3)
  float4 acc = make_float4(0.f, 0.f, 0.f, 0.f);
  for (int base = beg; base < end; base += 64) {
    int cnt = min(64, end - base);
    int mysrc = 0;
    float w = 0.f;
    if (base + lane < end) {
      mysrc = srcs[base + lane];
      float e = a_s[mysrc] + ad;
      e = (e >= 0.f) ? e : NEG_SLOPE * e;
      w = expf(e - m) / s;
    }
    for (int j = 0; j < cnt; ++j) {
      float alpha = __shfl(w, j, 64);
      int   sj    = __shfl(mysrc, j, 64);
      float4 hv = *(const float4*)&h[(size_t)sj * DIM + lane * 4];
      acc.x = fmaf(alpha, hv.x, acc.x);
      acc.y = fmaf(alpha, hv.y, acc.y);
      acc.z = fmaf(alpha, hv.z, acc.z);
      acc.w = fmaf(alpha, hv.w, acc.w);
    }
  }
  float4 bv = *(const float4*)&bias[lane * 4];
  acc.x += bv.x; acc.y += bv.y; acc.z += bv.z; acc.w += bv.w;
  *(float4*)&xout[(size_t)n * DIM + lane * 4] = acc;
}

// ---------------- expand adj bytes → symmetric 128x128 output ----------------
__global__ __launch_bounds__(256) void k_expand(const uint8_t* __restrict__ adjb,
                                                float* __restrict__ out) {
  int n = blockIdx.x;
  const uint8_t* ab = adjb + (size_t)n * NPAIRS;
  float4* o = (float4*)(out + (size_t)n * 16384);
  for (int q = threadIdx.x; q < 4096; q += 256) {
    int i = q >> 5;            // row
    int j0 = (q & 31) * 4;
    float v[4];
    #pragma unroll
    for (int j = 0; j < 4; ++j) {
      int jj = j0 + j;
      float x = 0.f;
      if (i < jj)      x = (float)ab[i * (255 - i) / 2 + (jj - i - 1)];
      else if (i > jj) x = (float)ab[jj * (255 - jj) / 2 + (i - jj - 1)];
      v[j] = x;
    }
    o[q] = make_float4(v[0], v[1], v[2], v[3]);
  }
}

extern "C" void kernel_launch(void* const* d_in, const int* in_sizes, int n_in,
                              void* d_out, int out_size, void* d_ws, size_t ws_size,
                              hipStream_t stream) {
  const float* x      = (const float*)d_in[0];
  const int*   ei     = (const int*)d_in[1];
  const float* gumbel = (const float*)d_in[2];
  const float* gatW   = (const float*)d_in[3];
  const float* a_src  = (const float*)d_in[4];
  const float* a_dst  = (const float*)d_in[5];
  const float* gatB   = (const float*)d_in[6];
  const float* fcW    = (const float*)d_in[7];
  const float* fcb    = (const float*)d_in[8];
  float* out = (float*)d_out;

  char* ws = (char*)d_ws;
  size_t off = 0;
  auto alloc = [&](size_t bytes) -> void* {
    void* p = ws + off;
    off += (bytes + 255) & ~(size_t)255;
    return p;
  };
  float* xb0   = (float*)alloc((size_t)NNODES * DIM * 4);
  float* xb1   = (float*)alloc((size_t)NNODES * DIM * 4);
  float* h     = (float*)alloc((size_t)NNODES * DIM * 4);
  float* At    = (float*)alloc((size_t)NNODES * DIM * 4);
  float* as_   = (float*)alloc(NNODES * 4);
  float* ad_   = (float*)alloc(NNODES * 4);
  int*   deg   = (int*)alloc(NNODES * 4);
  int*   offs  = (int*)alloc((NNODES + 1) * 4);
  int*   cursor= (int*)alloc(NNODES * 4);
  int*   srcs  = (int*)alloc((size_t)M_EDGES * 4);
  float* Wd    = (float*)alloc((size_t)DIM * NPAIRS * 4);
  float* cdf   = (float*)alloc(NPAIRS * 4);
  uint8_t* adjb= (uint8_t*)alloc((size_t)NNODES * NPAIRS);

  dim3 b256(256);

  hipMemsetAsync(deg, 0, NNODES * 4, stream);
  k_wdiff<<<dim3(32, DIM), b256, 0, stream>>>(fcW, fcb, Wd, cdf);
  k_deg<<<dim3((M_EDGES + 255) / 256), b256, 0, stream>>>(ei, deg);
  k_scan<<<dim3(1), dim3(1024), 0, stream>>>(deg, offs, cursor);
  k_scatter<<<dim3((M_EDGES + 255) / 256), b256, 0, stream>>>(ei, cursor, srcs);

  const float* xin = x;
  float* bufs[2] = {xb0, xb1};
  for (int l = 0; l < 3; ++l) {
    float* xout = bufs[l & 1];
    k_gemm_h<<<dim3(64, 4), b256, 0, stream>>>(xin, gatW + (size_t)l * DIM * DIM, h);
    k_rowdot<<<dim3(NNODES), b256, 0, stream>>>(h, a_src + (size_t)l * DIM,
                                                a_dst + (size_t)l * DIM, as_, ad_);
    k_agg<<<dim3(NNODES / 4), b256, 0, stream>>>(h, as_, ad_, offs, srcs,
                                                 gatB + (size_t)l * DIM, xout);
    xin = xout;
  }

  k_transp<<<dim3(64, 4), b256, 0, stream>>>(xin, At);
  k_gemm_pairs<<<dim3(16, 64), b256, 0, stream>>>(At, Wd, cdf, gumbel, adjb);
  k_expand<<<dim3(NNODES), b256, 0, stream>>>(adjb, out);
}

// Round 4
// 859.792 us; speedup vs baseline: 1.0954x; 1.0340x over previous
//
#include <hip/hip_runtime.h>
#include <cstdint>
#include <cstddef>

#define NNODES   4096        // B
#define DIM      256         // D
#define NPAIRS   8128        // 128*127/2
#define NPAD     8192        // padded pair columns (multiple of 128)
#define NEDGE_IN 131072      // E
#define M_EDGES  (NEDGE_IN + NNODES)
#define NEG_SLOPE 0.2f
#define EPS_G     1e-10f

#define AS3(p) ((__attribute__((address_space(3))) void*)(p))
#define AS1(p) ((const __attribute__((address_space(1))) void*)(p))

// ---------------- block reductions (256 threads = 4 waves) ----------------
__device__ __forceinline__ float blockReduceSum(float v, float* red) {
  #pragma unroll
  for (int o = 32; o > 0; o >>= 1) v += __shfl_down(v, o, 64);
  int lane = threadIdx.x & 63, wid = threadIdx.x >> 6;
  if (lane == 0) red[wid] = v;
  __syncthreads();
  if (threadIdx.x == 0) {
    float r = red[0];
    #pragma unroll
    for (int i = 1; i < 4; ++i) r += red[i];
    red[0] = r;
  }
  __syncthreads();
  float r = red[0];
  __syncthreads();
  return r;
}

// ---------------- CSR build ----------------
__global__ void k_deg(const int* __restrict__ ei, int* __restrict__ deg) {
  int e = blockIdx.x * 256 + threadIdx.x;
  if (e >= M_EDGES) return;
  int dst = (e < NEDGE_IN) ? ei[NEDGE_IN + e] : (e - NEDGE_IN);
  atomicAdd(&deg[dst], 1);
}

__global__ void k_scan(const int* __restrict__ deg, int* __restrict__ offs,
                       int* __restrict__ cursor) {
  __shared__ int lds[1024];
  int t = threadIdx.x;
  int4 d = *(const int4*)&deg[t * 4];
  int s = d.x + d.y + d.z + d.w;
  lds[t] = s;
  __syncthreads();
  for (int off = 1; off < 1024; off <<= 1) {
    int v = 0;
    if (t >= off) v = lds[t - off];
    __syncthreads();
    if (t >= off) lds[t] += v;
    __syncthreads();
  }
  int base = lds[t] - s;               // exclusive prefix
  int o0 = base, o1 = o0 + d.x, o2 = o1 + d.y, o3 = o2 + d.z;
  offs[t*4+0] = o0; offs[t*4+1] = o1; offs[t*4+2] = o2; offs[t*4+3] = o3;
  cursor[t*4+0] = o0; cursor[t*4+1] = o1; cursor[t*4+2] = o2; cursor[t*4+3] = o3;
  if (t == 1023) offs[4096] = lds[1023];
}

__global__ void k_scatter(const int* __restrict__ ei, int* __restrict__ cursor,
                          int* __restrict__ srcs) {
  int e = blockIdx.x * 256 + threadIdx.x;
  if (e >= M_EDGES) return;
  int src, dst;
  if (e < NEDGE_IN) { src = ei[e]; dst = ei[NEDGE_IN + e]; }
  else              { src = dst = e - NEDGE_IN; }
  int pos = atomicAdd(&cursor[dst], 1);
  srcs[pos] = src;
}

// ---------------- Wdiff / cdiff precompute (padded to NPAD cols) ----------------
__global__ void k_wdiff(const float* __restrict__ fcW, const float* __restrict__ fcb,
                        float* __restrict__ Wd, float* __restrict__ cdf) {
  int p = blockIdx.x * 256 + threadIdx.x;   // 0..8191
  int k = blockIdx.y;
  if (p < NPAIRS) {
    Wd[(size_t)k * NPAD + p] =
        fcW[(size_t)k * (2 * NPAIRS) + 2 * p] - fcW[(size_t)k * (2 * NPAIRS) + 2 * p + 1];
    if (k == 0) cdf[p] = fcb[2 * p] - fcb[2 * p + 1];
  } else {
    Wd[(size_t)k * NPAD + p] = 0.f;
  }
}

// ---------------- transpose x (4096x256) -> At (256x4096) ----------------
__global__ __launch_bounds__(256) void k_transp(const float* __restrict__ A,
                                                float* __restrict__ At) {
  __shared__ float t[64][65];
  int bx = blockIdx.x * 64;   // row base (NNODES dim)
  int by = blockIdx.y * 64;   // col base (DIM dim)
  for (int i = threadIdx.x; i < 4096; i += 256) {
    int r = i >> 6, c = i & 63;
    t[r][c] = A[(size_t)(bx + r) * DIM + by + c];
  }
  __syncthreads();
  for (int i = threadIdx.x; i < 4096; i += 256) {
    int r = i >> 6, c = i & 63;
    At[(size_t)(by + r) * NNODES + bx + c] = t[c][r];
  }
}

// ---------------- fp32 tiled GEMM: C(Mx256) = A(Mx256) * B(256x256) ----------------
__global__ __launch_bounds__(256) void k_gemm_h(const float* __restrict__ A,
                                                const float* __restrict__ Bm,
                                                float* __restrict__ C) {
  __shared__ float As[16][64];
  __shared__ float Bs[16][64];
  int tid = threadIdx.x;
  int rowBase = blockIdx.x * 64, colBase = blockIdx.y * 64;
  int tx = tid & 15, ty = tid >> 4;
  int ar = tid >> 2, ac = (tid & 3) << 2;
  int bkr = tid >> 6, bcc = tid & 63;
  float acc[4][4] = {{0.f}};
  for (int k0 = 0; k0 < DIM; k0 += 16) {
    float4 av = *(const float4*)&A[(size_t)(rowBase + ar) * DIM + k0 + ac];
    As[ac+0][ar] = av.x; As[ac+1][ar] = av.y; As[ac+2][ar] = av.z; As[ac+3][ar] = av.w;
    #pragma unroll
    for (int j = 0; j < 4; ++j)
      Bs[bkr + 4*j][bcc] = Bm[(size_t)(k0 + bkr + 4*j) * 256 + colBase + bcc];
    __syncthreads();
    #pragma unroll
    for (int kk = 0; kk < 16; ++kk) {
      float4 a4 = *(const float4*)&As[kk][ty << 2];
      float4 b4 = *(const float4*)&Bs[kk][tx << 2];
      float a[4] = {a4.x, a4.y, a4.z, a4.w};
      float b[4] = {b4.x, b4.y, b4.z, b4.w};
      #pragma unroll
      for (int i = 0; i < 4; ++i)
        #pragma unroll
        for (int j = 0; j < 4; ++j) acc[i][j] = fmaf(a[i], b[j], acc[i][j]);
    }
    __syncthreads();
  }
  #pragma unroll
  for (int i = 0; i < 4; ++i) {
    int r = rowBase + (ty << 2) + i;
    #pragma unroll
    for (int j = 0; j < 4; ++j)
      C[(size_t)r * 256 + colBase + (tx << 2) + j] = acc[i][j];
  }
}

// ------- pair GEMM (128x128 tile, 8x8/thread) with global_load_lds staging -------
// At: k-major (256 x 4096). Wd: padded (256 x NPAD). Output: adj bytes.
__global__ __launch_bounds__(256) void k_gemm_pairs(const float* __restrict__ At,
                                                    const float* __restrict__ Wd,
                                                    const float* __restrict__ cdf,
                                                    const float* __restrict__ gumbel,
                                                    uint8_t* __restrict__ adjb) {
  __shared__ float As[16][128];   // 8 KB
  __shared__ float Bs[16][128];   // 8 KB
  int tid = threadIdx.x;
  int tx = tid & 15, ty = tid >> 4;
  int rowBase = blockIdx.x * 128, colBase = blockIdx.y * 128;

  int wv  = tid >> 6;             // wave 0..3
  int ln  = tid & 63;
  int sub = ln >> 5;              // 0/1: which k-row within the 1KB DMA
  int lc  = (ln & 31) << 2;       // float col 0..124

  // wave w, issue q stages k-rows {4w+2q, 4w+2q+1} of both tiles
  int r0 = 4 * wv + sub;          // q=0 source row (per lane)
  int r1 = 4 * wv + 2 + sub;      // q=1 source row (per lane)
  float* ldsA0 = &As[4 * wv][0];
  float* ldsA1 = &As[4 * wv + 2][0];
  float* ldsB0 = &Bs[4 * wv][0];
  float* ldsB1 = &Bs[4 * wv + 2][0];

  const float* gA0 = At + (size_t)r0 * NNODES + rowBase + lc;
  const float* gA1 = At + (size_t)r1 * NNODES + rowBase + lc;
  const float* gB0 = Wd + (size_t)r0 * NPAD + colBase + lc;
  const float* gB1 = Wd + (size_t)r1 * NPAD + colBase + lc;

  float acc[4][16];
  #pragma unroll
  for (int q = 0; q < 4; ++q)
    #pragma unroll
    for (int r = 0; r < 16; ++r) acc[q][r] = 0.f;

  for (int k0 = 0; k0 < DIM; k0 += 16) {
    __syncthreads();
    __builtin_amdgcn_global_load_lds(AS1(gA0 + (size_t)k0 * NNODES), AS3(ldsA0), 16, 0, 0);
    __builtin_amdgcn_global_load_lds(AS1(gA1 + (size_t)k0 * NNODES), AS3(ldsA1), 16, 0, 0);
    __builtin_amdgcn_global_load_lds(AS1(gB0 + (size_t)k0 * NPAD),   AS3(ldsB0), 16, 0, 0);
    __builtin_amdgcn_global_load_lds(AS1(gB1 + (size_t)k0 * NPAD),   AS3(ldsB1), 16, 0, 0);
    __syncthreads();
    #pragma unroll
    for (int kk = 0; kk < 16; ++kk) {
      float4 a0 = *(const float4*)&As[kk][ty * 4];
      float4 a1 = *(const float4*)&As[kk][64 + ty * 4];
      float4 b0 = *(const float4*)&Bs[kk][tx * 4];
      float4 b1 = *(const float4*)&Bs[kk][64 + tx * 4];
      float av[8] = {a0.x,a0.y,a0.z,a0.w, a1.x,a1.y,a1.z,a1.w};
      float bv[8] = {b0.x,b0.y,b0.z,b0.w, b1.x,b1.y,b1.z,b1.w};
      #pragma unroll
      for (int ih = 0; ih < 2; ++ih)
        #pragma unroll
        for (int jh = 0; jh < 2; ++jh)
          #pragma unroll
          for (int i = 0; i < 4; ++i)
            #pragma unroll
            for (int j = 0; j < 4; ++j)
              acc[ih*2+jh][i*4+j] = fmaf(av[ih*4+i], bv[jh*4+j], acc[ih*2+jh][i*4+j]);
    }
  }

  // epilogue: dlt = acc + cdiff; keep = dlt >= g1-g0
  #pragma unroll
  for (int ih = 0; ih < 2; ++ih) {
    #pragma unroll
    for (int i = 0; i < 4; ++i) {
      int r = rowBase + ih * 64 + ty * 4 + i;
      #pragma unroll
      for (int jh = 0; jh < 2; ++jh) {
        int cb = colBase + jh * 64 + tx * 4;
        if (cb < NPAIRS) {
          const float4* gp = (const float4*)&gumbel[((size_t)r * NPAIRS + cb) * 2];
          float4 g01 = gp[0];
          float4 g23 = gp[1];
          float u0[4] = {g01.x, g01.z, g23.x, g23.z};
          float u1[4] = {g01.y, g01.w, g23.y, g23.w};
          uint8_t res[4];
          #pragma unroll
          for (int j = 0; j < 4; ++j) {
            float dlt = acc[ih*2+jh][i*4+j] + cdf[cb + j];
            float g0 = -logf(-logf(u0[j] + EPS_G) + EPS_G);
            float g1 = -logf(-logf(u1[j] + EPS_G) + EPS_G);
            res[j] = (dlt >= (g1 - g0)) ? (uint8_t)1 : (uint8_t)0;
          }
          *(uchar4*)&adjb[(size_t)r * NPAIRS + cb] =
              make_uchar4(res[0], res[1], res[2], res[3]);
        }
      }
    }
  }
}

// ---------------- per-row attention dots ----------------
__global__ __launch_bounds__(256) void k_rowdot(const float* __restrict__ h,
                                                const float* __restrict__ asrc,
                                                const float* __restrict__ adst,
                                                float* __restrict__ a_s,
                                                float* __restrict__ a_d) {
  __shared__ float red[4];
  int n = blockIdx.x, t = threadIdx.x;
  float hv = h[(size_t)n * DIM + t];
  float vs = blockReduceSum(hv * asrc[t], red);
  float vd = blockReduceSum(hv * adst[t], red);
  if (t == 0) { a_s[n] = vs; a_d[n] = vd; }
}

// ------- segment softmax + aggregation: one WAVE per dst node, float4 lanes -------
__global__ __launch_bounds__(256) void k_agg(const float* __restrict__ h,
                                             const float* __restrict__ a_s,
                                             const float* __restrict__ a_d,
                                             const int* __restrict__ offs,
                                             const int* __restrict__ srcs,
                                             const float* __restrict__ bias,
                                             float* __restrict__ xout) {
  int wid  = threadIdx.x >> 6;
  int lane = threadIdx.x & 63;
  int n = blockIdx.x * 4 + wid;
  int beg = offs[n], end = offs[n + 1];
  float ad = a_d[n];

  float m = -3.0e38f;
  for (int i = beg + lane; i < end; i += 64) {
    float e = a_s[srcs[i]] + ad;
    e = (e >= 0.f) ? e : NEG_SLOPE * e;
    m = fmaxf(m, e);
  }
  #pragma unroll
  for (int o = 1; o < 64; o <<= 1) m = fmaxf(m, __shfl_xor(m, o, 64));

  float s = 0.f;
  for (int i = beg + lane; i < end; i += 64) {
    float e = a_s[srcs[i]] + ad;
    e = (e >= 0.f) ? e : NEG_SLOPE * e;
    s += expf(e - m);
  }
  #pragma unroll
  for (int o = 1; o < 64; o <<= 1) s += __shfl_xor(s, o, 64);

  float4 acc = make_float4(0.f, 0.f, 0.f, 0.f);
  for (int base = beg; base < end; base += 64) {
    int cnt = min(64, end - base);
    int mysrc = 0;
    float w = 0.f;
    if (base + lane < end) {
      mysrc = srcs[base + lane];
      float e = a_s[mysrc] + ad;
      e = (e >= 0.f) ? e : NEG_SLOPE * e;
      w = expf(e - m) / s;
    }
    for (int j = 0; j < cnt; ++j) {
      float alpha = __shfl(w, j, 64);
      int   sj    = __shfl(mysrc, j, 64);
      float4 hv = *(const float4*)&h[(size_t)sj * DIM + lane * 4];
      acc.x = fmaf(alpha, hv.x, acc.x);
      acc.y = fmaf(alpha, hv.y, acc.y);
      acc.z = fmaf(alpha, hv.z, acc.z);
      acc.w = fmaf(alpha, hv.w, acc.w);
    }
  }
  float4 bv = *(const float4*)&bias[lane * 4];
  acc.x += bv.x; acc.y += bv.y; acc.z += bv.z; acc.w += bv.w;
  *(float4*)&xout[(size_t)n * DIM + lane * 4] = acc;
}

// ---------------- expand adj bytes → symmetric 128x128 output ----------------
__global__ __launch_bounds__(256) void k_expand(const uint8_t* __restrict__ adjb,
                                                float* __restrict__ out) {
  int n = blockIdx.x;
  const uint8_t* ab = adjb + (size_t)n * NPAIRS;
  float4* o = (float4*)(out + (size_t)n * 16384);
  for (int q = threadIdx.x; q < 4096; q += 256) {
    int i = q >> 5;            // row
    int j0 = (q & 31) * 4;
    float v[4];
    #pragma unroll
    for (int j = 0; j < 4; ++j) {
      int jj = j0 + j;
      float x = 0.f;
      if (i < jj)      x = (float)ab[i * (255 - i) / 2 + (jj - i - 1)];
      else if (i > jj) x = (float)ab[jj * (255 - jj) / 2 + (i - jj - 1)];
      v[j] = x;
    }
    o[q] = make_float4(v[0], v[1], v[2], v[3]);
  }
}

extern "C" void kernel_launch(void* const* d_in, const int* in_sizes, int n_in,
                              void* d_out, int out_size, void* d_ws, size_t ws_size,
                              hipStream_t stream) {
  const float* x      = (const float*)d_in[0];
  const int*   ei     = (const int*)d_in[1];
  const float* gumbel = (const float*)d_in[2];
  const float* gatW   = (const float*)d_in[3];
  const float* a_src  = (const float*)d_in[4];
  const float* a_dst  = (const float*)d_in[5];
  const float* gatB   = (const float*)d_in[6];
  const float* fcW    = (const float*)d_in[7];
  const float* fcb    = (const float*)d_in[8];
  float* out = (float*)d_out;

  char* ws = (char*)d_ws;
  size_t off = 0;
  auto alloc = [&](size_t bytes) -> void* {
    void* p = ws + off;
    off += (bytes + 255) & ~(size_t)255;
    return p;
  };
  float* xb0   = (float*)alloc((size_t)NNODES * DIM * 4);
  float* xb1   = (float*)alloc((size_t)NNODES * DIM * 4);
  float* h     = (float*)alloc((size_t)NNODES * DIM * 4);
  float* At    = (float*)alloc((size_t)NNODES * DIM * 4);
  float* as_   = (float*)alloc(NNODES * 4);
  float* ad_   = (float*)alloc(NNODES * 4);
  int*   deg   = (int*)alloc(NNODES * 4);
  int*   offs  = (int*)alloc((NNODES + 1) * 4);
  int*   cursor= (int*)alloc(NNODES * 4);
  int*   srcs  = (int*)alloc((size_t)M_EDGES * 4);
  float* Wd    = (float*)alloc((size_t)DIM * NPAD * 4);
  float* cdf   = (float*)alloc(NPAIRS * 4);
  uint8_t* adjb= (uint8_t*)alloc((size_t)NNODES * NPAIRS);

  dim3 b256(256);

  hipMemsetAsync(deg, 0, NNODES * 4, stream);
  k_wdiff<<<dim3(32, DIM), b256, 0, stream>>>(fcW, fcb, Wd, cdf);
  k_deg<<<dim3((M_EDGES + 255) / 256), b256, 0, stream>>>(ei, deg);
  k_scan<<<dim3(1), dim3(1024), 0, stream>>>(deg, offs, cursor);
  k_scatter<<<dim3((M_EDGES + 255) / 256), b256, 0, stream>>>(ei, cursor, srcs);

  const float* xin = x;
  float* bufs[2] = {xb0, xb1};
  for (int l = 0; l < 3; ++l) {
    float* xout = bufs[l & 1];
    k_gemm_h<<<dim3(64, 4), b256, 0, stream>>>(xin, gatW + (size_t)l * DIM * DIM, h);
    k_rowdot<<<dim3(NNODES), b256, 0, stream>>>(h, a_src + (size_t)l * DIM,
                                                a_dst + (size_t)l * DIM, as_, ad_);
    k_agg<<<dim3(NNODES / 4), b256, 0, stream>>>(h, as_, ad_, offs, srcs,
                                                 gatB + (size_t)l * DIM, xout);
    xin = xout;
  }

  k_transp<<<dim3(64, 4), b256, 0, stream>>>(xin, At);
  k_gemm_pairs<<<dim3(32, 64), b256, 0, stream>>>(At, Wd, cdf, gumbel, adjb);
  k_expand<<<dim3(NNODES), b256, 0, stream>>>(adjb, out);
}

// Round 5
// 821.947 us; speedup vs baseline: 1.1458x; 1.0460x over previous
//
#include <hip/hip_runtime.h>
#include <cstdint>
#include <cstddef>

#define NNODES   4096        // B
#define DIM      256         // D
#define NPAIRS   8128        // 128*127/2
#define NPAD     8192        // padded pair columns (multiple of 128)
#define NEDGE_IN 131072      // E
#define M_EDGES  (NEDGE_IN + NNODES)
#define NEG_SLOPE 0.2f
#define EPS_G     1e-10f

#define AS3(p) ((__attribute__((address_space(3))) void*)(p))
#define AS1(p) ((const __attribute__((address_space(1))) void*)(p))

// ---------------- block reductions (256 threads = 4 waves) ----------------
__device__ __forceinline__ float blockReduceSum(float v, float* red) {
  #pragma unroll
  for (int o = 32; o > 0; o >>= 1) v += __shfl_down(v, o, 64);
  int lane = threadIdx.x & 63, wid = threadIdx.x >> 6;
  if (lane == 0) red[wid] = v;
  __syncthreads();
  if (threadIdx.x == 0) {
    float r = red[0];
    #pragma unroll
    for (int i = 1; i < 4; ++i) r += red[i];
    red[0] = r;
  }
  __syncthreads();
  float r = red[0];
  __syncthreads();
  return r;
}

// ---------------- CSR build ----------------
__global__ void k_deg(const int* __restrict__ ei, int* __restrict__ deg) {
  int e = blockIdx.x * 256 + threadIdx.x;
  if (e >= M_EDGES) return;
  int dst = (e < NEDGE_IN) ? ei[NEDGE_IN + e] : (e - NEDGE_IN);
  atomicAdd(&deg[dst], 1);
}

__global__ void k_scan(const int* __restrict__ deg, int* __restrict__ offs,
                       int* __restrict__ cursor) {
  __shared__ int lds[1024];
  int t = threadIdx.x;
  int4 d = *(const int4*)&deg[t * 4];
  int s = d.x + d.y + d.z + d.w;
  lds[t] = s;
  __syncthreads();
  for (int off = 1; off < 1024; off <<= 1) {
    int v = 0;
    if (t >= off) v = lds[t - off];
    __syncthreads();
    if (t >= off) lds[t] += v;
    __syncthreads();
  }
  int base = lds[t] - s;               // exclusive prefix
  int o0 = base, o1 = o0 + d.x, o2 = o1 + d.y, o3 = o2 + d.z;
  offs[t*4+0] = o0; offs[t*4+1] = o1; offs[t*4+2] = o2; offs[t*4+3] = o3;
  cursor[t*4+0] = o0; cursor[t*4+1] = o1; cursor[t*4+2] = o2; cursor[t*4+3] = o3;
  if (t == 1023) offs[4096] = lds[1023];
}

__global__ void k_scatter(const int* __restrict__ ei, int* __restrict__ cursor,
                          int* __restrict__ srcs) {
  int e = blockIdx.x * 256 + threadIdx.x;
  if (e >= M_EDGES) return;
  int src, dst;
  if (e < NEDGE_IN) { src = ei[e]; dst = ei[NEDGE_IN + e]; }
  else              { src = dst = e - NEDGE_IN; }
  int pos = atomicAdd(&cursor[dst], 1);
  srcs[pos] = src;
}

// ---------------- Wdiff / cdiff precompute (padded to NPAD cols) ----------------
__global__ void k_wdiff(const float* __restrict__ fcW, const float* __restrict__ fcb,
                        float* __restrict__ Wd, float* __restrict__ cdf) {
  int p = blockIdx.x * 256 + threadIdx.x;   // 0..8191
  int k = blockIdx.y;
  if (p < NPAIRS) {
    Wd[(size_t)k * NPAD + p] =
        fcW[(size_t)k * (2 * NPAIRS) + 2 * p] - fcW[(size_t)k * (2 * NPAIRS) + 2 * p + 1];
    if (k == 0) cdf[p] = fcb[2 * p] - fcb[2 * p + 1];
  } else {
    Wd[(size_t)k * NPAD + p] = 0.f;
  }
}

// ---------------- transpose x (4096x256) -> At (256x4096) ----------------
__global__ __launch_bounds__(256) void k_transp(const float* __restrict__ A,
                                                float* __restrict__ At) {
  __shared__ float t[64][65];
  int bx = blockIdx.x * 64;   // row base (NNODES dim)
  int by = blockIdx.y * 64;   // col base (DIM dim)
  for (int i = threadIdx.x; i < 4096; i += 256) {
    int r = i >> 6, c = i & 63;
    t[r][c] = A[(size_t)(bx + r) * DIM + by + c];
  }
  __syncthreads();
  for (int i = threadIdx.x; i < 4096; i += 256) {
    int r = i >> 6, c = i & 63;
    At[(size_t)(by + r) * NNODES + bx + c] = t[c][r];
  }
}

// ---------------- fp32 tiled GEMM: C(Mx256) = A(Mx256) * B(256x256) ----------------
__global__ __launch_bounds__(256) void k_gemm_h(const float* __restrict__ A,
                                                const float* __restrict__ Bm,
                                                float* __restrict__ C) {
  __shared__ float As[16][64];
  __shared__ float Bs[16][64];
  int tid = threadIdx.x;
  int rowBase = blockIdx.x * 64, colBase = blockIdx.y * 64;
  int tx = tid & 15, ty = tid >> 4;
  int ar = tid >> 2, ac = (tid & 3) << 2;
  int bkr = tid >> 6, bcc = tid & 63;
  float acc[4][4] = {{0.f}};
  for (int k0 = 0; k0 < DIM; k0 += 16) {
    float4 av = *(const float4*)&A[(size_t)(rowBase + ar) * DIM + k0 + ac];
    As[ac+0][ar] = av.x; As[ac+1][ar] = av.y; As[ac+2][ar] = av.z; As[ac+3][ar] = av.w;
    #pragma unroll
    for (int j = 0; j < 4; ++j)
      Bs[bkr + 4*j][bcc] = Bm[(size_t)(k0 + bkr + 4*j) * 256 + colBase + bcc];
    __syncthreads();
    #pragma unroll
    for (int kk = 0; kk < 16; ++kk) {
      float4 a4 = *(const float4*)&As[kk][ty << 2];
      float4 b4 = *(const float4*)&Bs[kk][tx << 2];
      float a[4] = {a4.x, a4.y, a4.z, a4.w};
      float b[4] = {b4.x, b4.y, b4.z, b4.w};
      #pragma unroll
      for (int i = 0; i < 4; ++i)
        #pragma unroll
        for (int j = 0; j < 4; ++j) acc[i][j] = fmaf(a[i], b[j], acc[i][j]);
    }
    __syncthreads();
  }
  #pragma unroll
  for (int i = 0; i < 4; ++i) {
    int r = rowBase + (ty << 2) + i;
    #pragma unroll
    for (int j = 0; j < 4; ++j)
      C[(size_t)r * 256 + colBase + (tx << 2) + j] = acc[i][j];
  }
}

// ------- pair GEMM (128x128 tile, BK=32, 8x8/thread) with global_load_lds -------
// At: k-major (256 x 4096). Wd: padded (256 x NPAD). Output: adj bytes.
__global__ __launch_bounds__(256, 4) void k_gemm_pairs(const float* __restrict__ At,
                                                       const float* __restrict__ Wd,
                                                       const float* __restrict__ cdf,
                                                       const float* __restrict__ gumbel,
                                                       uint8_t* __restrict__ adjb) {
  __shared__ float As[32][128];   // 16 KB
  __shared__ float Bs[32][128];   // 16 KB
  int tid = threadIdx.x;
  int tx = tid & 15, ty = tid >> 4;
  int rowBase = blockIdx.x * 128, colBase = blockIdx.y * 128;

  int wv  = tid >> 6;             // wave 0..3
  int ln  = tid & 63;
  int sub = ln >> 5;              // 0/1: which k-row within the 1KB DMA
  int lc  = (ln & 31) << 2;       // float col 0..124

  float acc[4][16];
  #pragma unroll
  for (int q = 0; q < 4; ++q)
    #pragma unroll
    for (int r = 0; r < 16; ++r) acc[q][r] = 0.f;

  for (int k0 = 0; k0 < DIM; k0 += 32) {
    __syncthreads();
    #pragma unroll
    for (int q = 0; q < 4; ++q) {
      int r = 8 * wv + 2 * q + sub;      // k-row this lane sources
      __builtin_amdgcn_global_load_lds(
          AS1(At + (size_t)(k0 + r) * NNODES + rowBase + lc),
          AS3(&As[8 * wv + 2 * q][0]), 16, 0, 0);
      __builtin_amdgcn_global_load_lds(
          AS1(Wd + (size_t)(k0 + r) * NPAD + colBase + lc),
          AS3(&Bs[8 * wv + 2 * q][0]), 16, 0, 0);
    }
    __syncthreads();
    #pragma unroll 16
    for (int kk = 0; kk < 32; ++kk) {
      float4 a0 = *(const float4*)&As[kk][ty * 4];
      float4 a1 = *(const float4*)&As[kk][64 + ty * 4];
      float4 b0 = *(const float4*)&Bs[kk][tx * 4];
      float4 b1 = *(const float4*)&Bs[kk][64 + tx * 4];
      float av[8] = {a0.x,a0.y,a0.z,a0.w, a1.x,a1.y,a1.z,a1.w};
      float bv[8] = {b0.x,b0.y,b0.z,b0.w, b1.x,b1.y,b1.z,b1.w};
      #pragma unroll
      for (int ih = 0; ih < 2; ++ih)
        #pragma unroll
        for (int jh = 0; jh < 2; ++jh)
          #pragma unroll
          for (int i = 0; i < 4; ++i)
            #pragma unroll
            for (int j = 0; j < 4; ++j)
              acc[ih*2+jh][i*4+j] = fmaf(av[ih*4+i], bv[jh*4+j], acc[ih*2+jh][i*4+j]);
    }
  }

  // epilogue: dlt >= g1-g0, with g1-g0 = log(l0/l1), li = eps - log(ui+eps)
  #pragma unroll
  for (int ih = 0; ih < 2; ++ih) {
    #pragma unroll
    for (int i = 0; i < 4; ++i) {
      int r = rowBase + ih * 64 + ty * 4 + i;
      #pragma unroll
      for (int jh = 0; jh < 2; ++jh) {
        int cb = colBase + jh * 64 + tx * 4;
        if (cb < NPAIRS) {
          const float4* gp = (const float4*)&gumbel[((size_t)r * NPAIRS + cb) * 2];
          float4 g01 = gp[0];
          float4 g23 = gp[1];
          float u0[4] = {g01.x, g01.z, g23.x, g23.z};
          float u1[4] = {g01.y, g01.w, g23.y, g23.w};
          uint8_t res[4];
          #pragma unroll
          for (int j = 0; j < 4; ++j) {
            float dlt = acc[ih*2+jh][i*4+j] + cdf[cb + j];
            float l0 = EPS_G - logf(u0[j] + EPS_G);
            float l1 = EPS_G - logf(u1[j] + EPS_G);
            res[j] = (dlt >= logf(l0 / l1)) ? (uint8_t)1 : (uint8_t)0;
          }
          *(uchar4*)&adjb[(size_t)r * NPAIRS + cb] =
              make_uchar4(res[0], res[1], res[2], res[3]);
        }
      }
    }
  }
}

// ---------------- per-row attention dots: one wave per node ----------------
__global__ __launch_bounds__(256) void k_rowdot(const float* __restrict__ h,
                                                const float* __restrict__ asrc,
                                                const float* __restrict__ adst,
                                                float* __restrict__ a_s,
                                                float* __restrict__ a_d) {
  int wid = threadIdx.x >> 6, lane = threadIdx.x & 63;
  int n = blockIdx.x * 4 + wid;
  float4 hv = *(const float4*)&h[(size_t)n * DIM + lane * 4];
  float4 s4 = *(const float4*)&asrc[lane * 4];
  float4 d4 = *(const float4*)&adst[lane * 4];
  float vs = hv.x*s4.x + hv.y*s4.y + hv.z*s4.z + hv.w*s4.w;
  float vd = hv.x*d4.x + hv.y*d4.y + hv.z*d4.z + hv.w*d4.w;
  #pragma unroll
  for (int o = 1; o < 64; o <<= 1) {
    vs += __shfl_xor(vs, o, 64);
    vd += __shfl_xor(vd, o, 64);
  }
  if (lane == 0) { a_s[n] = vs; a_d[n] = vd; }
}

// ------- segment softmax + aggregation: one WAVE per dst node, float4 lanes -------
__global__ __launch_bounds__(256) void k_agg(const float* __restrict__ h,
                                             const float* __restrict__ a_s,
                                             const float* __restrict__ a_d,
                                             const int* __restrict__ offs,
                                             const int* __restrict__ srcs,
                                             const float* __restrict__ bias,
                                             float* __restrict__ xout) {
  int wid  = threadIdx.x >> 6;
  int lane = threadIdx.x & 63;
  int n = blockIdx.x * 4 + wid;
  int beg = offs[n], end = offs[n + 1];
  float ad = a_d[n];

  float m = -3.0e38f;
  for (int i = beg + lane; i < end; i += 64) {
    float e = a_s[srcs[i]] + ad;
    e = (e >= 0.f) ? e : NEG_SLOPE * e;
    m = fmaxf(m, e);
  }
  #pragma unroll
  for (int o = 1; o < 64; o <<= 1) m = fmaxf(m, __shfl_xor(m, o, 64));

  float s = 0.f;
  for (int i = beg + lane; i < end; i += 64) {
    float e = a_s[srcs[i]] + ad;
    e = (e >= 0.f) ? e : NEG_SLOPE * e;
    s += expf(e - m);
  }
  #pragma unroll
  for (int o = 1; o < 64; o <<= 1) s += __shfl_xor(s, o, 64);

  float4 acc = make_float4(0.f, 0.f, 0.f, 0.f);
  for (int base = beg; base < end; base += 64) {
    int cnt = min(64, end - base);
    int mysrc = 0;
    float w = 0.f;
    if (base + lane < end) {
      mysrc = srcs[base + lane];
      float e = a_s[mysrc] + ad;
      e = (e >= 0.f) ? e : NEG_SLOPE * e;
      w = expf(e - m) / s;
    }
    int j = 0;
    for (; j + 4 <= cnt; j += 4) {
      float al0 = __shfl(w, j,     64), al1 = __shfl(w, j + 1, 64);
      float al2 = __shfl(w, j + 2, 64), al3 = __shfl(w, j + 3, 64);
      int   s0  = __shfl(mysrc, j,     64), s1 = __shfl(mysrc, j + 1, 64);
      int   s2  = __shfl(mysrc, j + 2, 64), s3 = __shfl(mysrc, j + 3, 64);
      float4 h0 = *(const float4*)&h[(size_t)s0 * DIM + lane * 4];
      float4 h1 = *(const float4*)&h[(size_t)s1 * DIM + lane * 4];
      float4 h2 = *(const float4*)&h[(size_t)s2 * DIM + lane * 4];
      float4 h3 = *(const float4*)&h[(size_t)s3 * DIM + lane * 4];
      acc.x = fmaf(al0, h0.x, fmaf(al1, h1.x, fmaf(al2, h2.x, fmaf(al3, h3.x, acc.x))));
      acc.y = fmaf(al0, h0.y, fmaf(al1, h1.y, fmaf(al2, h2.y, fmaf(al3, h3.y, acc.y))));
      acc.z = fmaf(al0, h0.z, fmaf(al1, h1.z, fmaf(al2, h2.z, fmaf(al3, h3.z, acc.z))));
      acc.w = fmaf(al0, h0.w, fmaf(al1, h1.w, fmaf(al2, h2.w, fmaf(al3, h3.w, acc.w))));
    }
    for (; j < cnt; ++j) {
      float alpha = __shfl(w, j, 64);
      int   sj    = __shfl(mysrc, j, 64);
      float4 hv = *(const float4*)&h[(size_t)sj * DIM + lane * 4];
      acc.x = fmaf(alpha, hv.x, acc.x);
      acc.y = fmaf(alpha, hv.y, acc.y);
      acc.z = fmaf(alpha, hv.z, acc.z);
      acc.w = fmaf(alpha, hv.w, acc.w);
    }
  }
  float4 bv = *(const float4*)&bias[lane * 4];
  acc.x += bv.x; acc.y += bv.y; acc.z += bv.z; acc.w += bv.w;
  *(float4*)&xout[(size_t)n * DIM + lane * 4] = acc;
}

// ---------------- expand adj bytes → symmetric 128x128 output ----------------
__global__ __launch_bounds__(256) void k_expand(const uint8_t* __restrict__ adjb,
                                                float* __restrict__ out) {
  int n = blockIdx.x;
  const uint8_t* ab = adjb + (size_t)n * NPAIRS;
  float4* o = (float4*)(out + (size_t)n * 16384);
  for (int q = threadIdx.x; q < 4096; q += 256) {
    int i = q >> 5;            // row
    int j0 = (q & 31) * 4;
    float v[4];
    #pragma unroll
    for (int j = 0; j < 4; ++j) {
      int jj = j0 + j;
      float x = 0.f;
      if (i < jj)      x = (float)ab[i * (255 - i) / 2 + (jj - i - 1)];
      else if (i > jj) x = (float)ab[jj * (255 - jj) / 2 + (i - jj - 1)];
      v[j] = x;
    }
    o[q] = make_float4(v[0], v[1], v[2], v[3]);
  }
}

extern "C" void kernel_launch(void* const* d_in, const int* in_sizes, int n_in,
                              void* d_out, int out_size, void* d_ws, size_t ws_size,
                              hipStream_t stream) {
  const float* x      = (const float*)d_in[0];
  const int*   ei     = (const int*)d_in[1];
  const float* gumbel = (const float*)d_in[2];
  const float* gatW   = (const float*)d_in[3];
  const float* a_src  = (const float*)d_in[4];
  const float* a_dst  = (const float*)d_in[5];
  const float* gatB   = (const float*)d_in[6];
  const float* fcW    = (const float*)d_in[7];
  const float* fcb    = (const float*)d_in[8];
  float* out = (float*)d_out;

  char* ws = (char*)d_ws;
  size_t off = 0;
  auto alloc = [&](size_t bytes) -> void* {
    void* p = ws + off;
    off += (bytes + 255) & ~(size_t)255;
    return p;
  };
  float* xb0   = (float*)alloc((size_t)NNODES * DIM * 4);
  float* xb1   = (float*)alloc((size_t)NNODES * DIM * 4);
  float* h     = (float*)alloc((size_t)NNODES * DIM * 4);
  float* At    = (float*)alloc((size_t)NNODES * DIM * 4);
  float* as_   = (float*)alloc(NNODES * 4);
  float* ad_   = (float*)alloc(NNODES * 4);
  int*   deg   = (int*)alloc(NNODES * 4);
  int*   offs  = (int*)alloc((NNODES + 1) * 4);
  int*   cursor= (int*)alloc(NNODES * 4);
  int*   srcs  = (int*)alloc((size_t)M_EDGES * 4);
  float* Wd    = (float*)alloc((size_t)DIM * NPAD * 4);
  float* cdf   = (float*)alloc(NPAIRS * 4);
  uint8_t* adjb= (uint8_t*)alloc((size_t)NNODES * NPAIRS);

  dim3 b256(256);

  hipMemsetAsync(deg, 0, NNODES * 4, stream);
  k_wdiff<<<dim3(32, DIM), b256, 0, stream>>>(fcW, fcb, Wd, cdf);
  k_deg<<<dim3((M_EDGES + 255) / 256), b256, 0, stream>>>(ei, deg);
  k_scan<<<dim3(1), dim3(1024), 0, stream>>>(deg, offs, cursor);
  k_scatter<<<dim3((M_EDGES + 255) / 256), b256, 0, stream>>>(ei, cursor, srcs);

  const float* xin = x;
  float* bufs[2] = {xb0, xb1};
  for (int l = 0; l < 3; ++l) {
    float* xout = bufs[l & 1];
    k_gemm_h<<<dim3(64, 4), b256, 0, stream>>>(xin, gatW + (size_t)l * DIM * DIM, h);
    k_rowdot<<<dim3(NNODES / 4), b256, 0, stream>>>(h, a_src + (size_t)l * DIM,
                                                    a_dst + (size_t)l * DIM, as_, ad_);
    k_agg<<<dim3(NNODES / 4), b256, 0, stream>>>(h, as_, ad_, offs, srcs,
                                                 gatB + (size_t)l * DIM, xout);
    xin = xout;
  }

  k_transp<<<dim3(64, 4), b256, 0, stream>>>(xin, At);
  k_gemm_pairs<<<dim3(32, 64), b256, 0, stream>>>(At, Wd, cdf, gumbel, adjb);
  k_expand<<<dim3(NNODES), b256, 0, stream>>>(adjb, out);
}